// Round 7
// baseline (215.388 us; speedup 1.0000x reference)
//
#include <hip/hip_runtime.h>
#include <hip/hip_bf16.h>

typedef __attribute__((ext_vector_type(4))) float f32x4;
typedef __attribute__((ext_vector_type(8))) short s16x8;
typedef __attribute__((ext_vector_type(4))) unsigned short u16x4;

__device__ __forceinline__ unsigned short f2bf(float f) {
  unsigned u = __builtin_bit_cast(unsigned, f);
  u += 0x7fffu + ((u >> 16) & 1u);
  return (unsigned short)(u >> 16);
}

// ---------------------------------------------------------------------------
// K1: mod[b][j] = silu(emb[b]) . ada_w[j] + ada_b[j]     (32 x 512), pure f32.
// ---------------------------------------------------------------------------
__global__ __launch_bounds__(512) void k_mod(const float* __restrict__ emb,
                                             const float* __restrict__ ada_w,
                                             const float* __restrict__ ada_b,
                                             float* __restrict__ mod) {
  __shared__ __align__(16) float semb[32][1028];  // silu(emb) f32, padded row (+4)
  const int t = threadIdx.x;
  for (int i = t; i < 8192; i += 512) {           // 8192 float4 = 32x1024
    f32x4 v = ((const f32x4*)emb)[i];
    f32x4 s;
#pragma unroll
    for (int j = 0; j < 4; ++j) s[j] = v[j] / (1.f + __expf(-v[j]));
    *(f32x4*)&semb[i >> 8][(i & 255) << 2] = s;
  }
  __syncthreads();
  const int jl = t >> 5, b = t & 31;
  const int j = blockIdx.x * 16 + jl;
  const f32x4* aw = (const f32x4*)(ada_w + (size_t)j * 1024);
  float acc = 0.f;
  for (int q = 0; q < 256; ++q) {
    f32x4 a = aw[q];
    f32x4 sv = *(const f32x4*)&semb[b][q * 4];
    acc += a[0] * sv[0] + a[1] * sv[1] + a[2] * sv[2] + a[3] * sv[3];
  }
  mod[b * 512 + j] = acc + ada_b[j];
}

// ---------------------------------------------------------------------------
// K2: W'[b][o][c] = conv_w[o][c]*(1+scale[b][c]) (bf16) in MFMA-frag staged
// layout (verified r2-r5). Also d[b][o] = sum_c conv_w[o][c]*shift[b][c]+conv_b.
// ---------------------------------------------------------------------------
__global__ __launch_bounds__(256) void k_prep(const float* __restrict__ mod,
                                              const float* __restrict__ conv_w,
                                              const float* __restrict__ conv_b,
                                              unsigned short* __restrict__ wp,
                                              float* __restrict__ dvec) {
  const int b = blockIdx.y;
  const int o = blockIdx.x * 4 + (threadIdx.x >> 6);
  const int l = threadIdx.x & 63;
  const float* sh = mod + b * 512;        // shift = first half
  const float* sc = mod + b * 512 + 256;  // scale = second half
  f32x4 cw = ((const f32x4*)(conv_w + (size_t)o * 256))[l];
  f32x4 s4 = ((const f32x4*)sc)[l];
  f32x4 h4 = ((const f32x4*)sh)[l];
  u16x4 wq;
#pragma unroll
  for (int j = 0; j < 4; ++j) wq[j] = f2bf(cw[j] * (1.f + s4[j]));
  const int wr = o >> 6, m = (o >> 4) & 3, lr = o & 15;
  const int kk = l >> 3, g = (l >> 1) & 3, jb = 4 * (l & 1);
  *(u16x4*)(wp + (size_t)b * 65536 + (((wr * 4 + m) * 8 + kk) * 512 + g * 128 + lr * 8 + jb)) = wq;
  float dd = cw[0] * h4[0] + cw[1] * h4[1] + cw[2] * h4[2] + cw[3] * h4[3];
#pragma unroll
  for (int off = 32; off; off >>= 1) dd += __shfl_down(dd, off);
  if (l == 0) dvec[b * 256 + o] = dd + conv_b[o];
}

// ---------------------------------------------------------------------------
// K3a (k_pre): streaming rms + transpose-convert.
// grid(16,32), 512 thr: block = (256-wide s-chunk, batch b).
// Reads x rows in 1KB contiguous spans (DRAM page-friendly);
// writes xT[b][s][c] bf16 (L3-destined) + rms_g[b][s].
// ---------------------------------------------------------------------------
__global__ __launch_bounds__(512) void k_pre(const float* __restrict__ x,
                                             unsigned short* __restrict__ xT,
                                             float* __restrict__ rms_g) {
  constexpr int HW = 4096;
  __shared__ float part[8][256];
  const int t = threadIdx.x;
  const int b = blockIdx.y;
  const int s0 = blockIdx.x * 256;
  const int w = t >> 6, lane = t & 63;
  const int cl = t >> 4;                  // c_local 0..31
  const int sq = t & 15;
  const float* xb = x + (size_t)b * (256 * HW) + s0;
  unsigned short* xTb = xT + ((size_t)b * HW + s0) * 256;

  f32x4 ss[4] = {};
#pragma unroll
  for (int cc = 0; cc < 8; ++cc) {
    const int c = cc * 32 + cl;
    const float* row = xb + (size_t)c * HW;
#pragma unroll
    for (int si = 0; si < 4; ++si) {
      f32x4 v = *(const f32x4*)(row + si * 64 + 4 * sq);
      ss[si] += v * v;
#pragma unroll
      for (int r = 0; r < 4; ++r)
        xTb[(size_t)(si * 64 + 4 * sq + r) * 256 + c] = f2bf(v[r]);
    }
  }
  // reduce over the wave's 4 c_local groups (lane bits 4,5)
#pragma unroll
  for (int off = 16; off <= 32; off <<= 1) {
#pragma unroll
    for (int si = 0; si < 4; ++si)
#pragma unroll
      for (int j = 0; j < 4; ++j) ss[si][j] += __shfl_xor(ss[si][j], off);
  }
  if (lane < 16) {
#pragma unroll
    for (int si = 0; si < 4; ++si) *(f32x4*)&part[w][si * 64 + 4 * sq] = ss[si];
  }
  __syncthreads();
  if (t < 256) {
    float sum = 0.f;
#pragma unroll
    for (int q = 0; q < 8; ++q) sum += part[q][t];
    rms_g[(size_t)b * HW + s0 + t] = rsqrtf(sum * (1.0f / 256.0f) + 1e-6f);
  }
}

// ---------------------------------------------------------------------------
// K3b (k_gemm): pure GEMM + selu epilogue. grid(32,32), 512 thr = 8 waves.
// Block tile 256(o) x 128(s); wave (wr=w>>1, wc=w&1) -> 64(o) x 64(s).
// NO LDS, NO barriers: A-frags from staged wp (L2-hot), B-frags straight
// from xT (L3-hot, k-contiguous), rms/d from global in the epilogue.
// ---------------------------------------------------------------------------
__global__ __launch_bounds__(512, 4) void k_gemm(const unsigned short* __restrict__ xT,
                                                 const unsigned short* __restrict__ wp,
                                                 const float* __restrict__ rms_g,
                                                 const float* __restrict__ dvec,
                                                 float* __restrict__ out) {
  constexpr int HW = 4096;
  const int t = threadIdx.x;
  const int b = blockIdx.y;
  const int w = t >> 6, lane = t & 63;
  const int wr = w >> 1, wc = w & 1;
  const int lr = lane & 15, g = lane >> 4;
  const int s0 = blockIdx.x * 128 + wc * 64;

  const unsigned short* A2 = wp + (size_t)b * 65536;
  const unsigned short* Bb = xT + ((size_t)b * HW + s0) * 256;

  f32x4 acc[4][4] = {};
#pragma unroll
  for (int kk = 0; kk < 8; ++kk) {
    s16x8 af[4];
#pragma unroll
    for (int m = 0; m < 4; ++m)
      af[m] = *(const s16x8*)(A2 + (((wr * 4 + m) * 8 + kk) * 512 + lane * 8));
    s16x8 bf[4];
#pragma unroll
    for (int n = 0; n < 4; ++n)
      bf[n] = *(const s16x8*)(Bb + (size_t)(16 * n + lr) * 256 + kk * 32 + g * 8);
#pragma unroll
    for (int m = 0; m < 4; ++m)
#pragma unroll
      for (int n = 0; n < 4; ++n)
        acc[m][n] = __builtin_amdgcn_mfma_f32_16x16x32_bf16(af[m], bf[n], acc[m][n], 0, 0, 0);
  }

  // ---- epilogue: y = rms*G + d; selu ----
  float rr[4];
#pragma unroll
  for (int n = 0; n < 4; ++n) rr[n] = rms_g[(size_t)b * HW + s0 + 16 * n + lr];
  float* ob = out + (size_t)b * (256 * HW) + s0;
#pragma unroll
  for (int m = 0; m < 4; ++m) {
    const int o0 = 64 * wr + 16 * m + 4 * g;
    const f32x4 dv = *(const f32x4*)(dvec + (size_t)b * 256 + o0);
#pragma unroll
    for (int n = 0; n < 4; ++n) {
#pragma unroll
      for (int r = 0; r < 4; ++r) {
        float v = rr[n] * acc[m][n][r] + dv[r];
        float res = v > 0.f ? 1.0507009873554805f * v
                            : 1.7580993408473766f * (__expf(v) - 1.f);
        ob[(size_t)(o0 + r) * HW + 16 * n + lr] = res;
      }
    }
  }
}

// ---------------------------------------------------------------------------
extern "C" void kernel_launch(void* const* d_in, const int* in_sizes, int n_in,
                              void* d_out, int out_size, void* d_ws, size_t ws_size,
                              hipStream_t stream) {
  const float* x      = (const float*)d_in[0];
  const float* emb    = (const float*)d_in[1];
  const float* ada_w  = (const float*)d_in[2];
  const float* ada_b  = (const float*)d_in[3];
  const float* conv_w = (const float*)d_in[4];
  const float* conv_b = (const float*)d_in[5];
  float* out = (float*)d_out;

  float* mod   = (float*)d_ws;                    // 32*512 f32      (64 KB)
  float* dvec  = mod + 32 * 512;                  // 32*256 f32      (32 KB)
  float* rms_g = dvec + 32 * 256;                 // 32*4096 f32     (512 KB)
  unsigned short* wp = (unsigned short*)(rms_g + 32 * 4096);  // 32*256*256 bf16 (4 MB)
  unsigned short* xT = wp + (size_t)32 * 256 * 256;           // 32*4096*256 bf16 (64 MB)

  k_mod<<<dim3(32), 512, 0, stream>>>(emb, ada_w, ada_b, mod);
  k_prep<<<dim3(64, 32), 256, 0, stream>>>(mod, conv_w, conv_b, wp, dvec);
  k_pre<<<dim3(16, 32), 512, 0, stream>>>(x, xT, rms_g);
  k_gemm<<<dim3(32, 32), 512, 0, stream>>>(xT, wp, rms_g, dvec, out);
}

// Round 8
// 99.260 us; speedup vs baseline: 2.1699x; 2.1699x over previous
//
#include <hip/hip_runtime.h>
#include <hip/hip_bf16.h>

typedef __attribute__((ext_vector_type(4))) float f32x4;
typedef __attribute__((ext_vector_type(8))) short s16x8;
typedef __attribute__((ext_vector_type(4))) unsigned short u16x4;

__device__ __forceinline__ unsigned short f2bf(float f) {
  unsigned u = __builtin_bit_cast(unsigned, f);
  u += 0x7fffu + ((u >> 16) & 1u);
  return (unsigned short)(u >> 16);
}

// ---------------------------------------------------------------------------
// K1: mod[b][j] = silu(emb[b]) . ada_w[j] + ada_b[j]     (32 x 512), pure f32.
// ---------------------------------------------------------------------------
__global__ __launch_bounds__(512) void k_mod(const float* __restrict__ emb,
                                             const float* __restrict__ ada_w,
                                             const float* __restrict__ ada_b,
                                             float* __restrict__ mod) {
  __shared__ __align__(16) float semb[32][1028];  // silu(emb) f32, padded row (+4)
  const int t = threadIdx.x;
  for (int i = t; i < 8192; i += 512) {           // 8192 float4 = 32x1024
    f32x4 v = ((const f32x4*)emb)[i];
    f32x4 s;
#pragma unroll
    for (int j = 0; j < 4; ++j) s[j] = v[j] / (1.f + __expf(-v[j]));
    *(f32x4*)&semb[i >> 8][(i & 255) << 2] = s;
  }
  __syncthreads();
  const int jl = t >> 5, b = t & 31;
  const int j = blockIdx.x * 16 + jl;
  const f32x4* aw = (const f32x4*)(ada_w + (size_t)j * 1024);
  float acc = 0.f;
  for (int q = 0; q < 256; ++q) {
    f32x4 a = aw[q];
    f32x4 sv = *(const f32x4*)&semb[b][q * 4];
    acc += a[0] * sv[0] + a[1] * sv[1] + a[2] * sv[2] + a[3] * sv[3];
  }
  mod[b * 512 + j] = acc + ada_b[j];
}

// ---------------------------------------------------------------------------
// K2: W'[b][o][c] = conv_w[o][c]*(1+scale[b][c]) (bf16) in MFMA-frag staged
// layout (verified r2-r7). Also d[b][o] = sum_c conv_w[o][c]*shift[b][c]+conv_b.
// ---------------------------------------------------------------------------
__global__ __launch_bounds__(256) void k_prep(const float* __restrict__ mod,
                                              const float* __restrict__ conv_w,
                                              const float* __restrict__ conv_b,
                                              unsigned short* __restrict__ wp,
                                              float* __restrict__ dvec) {
  const int b = blockIdx.y;
  const int o = blockIdx.x * 4 + (threadIdx.x >> 6);
  const int l = threadIdx.x & 63;
  const float* sh = mod + b * 512;        // shift = first half
  const float* sc = mod + b * 512 + 256;  // scale = second half
  f32x4 cw = ((const f32x4*)(conv_w + (size_t)o * 256))[l];
  f32x4 s4 = ((const f32x4*)sc)[l];
  f32x4 h4 = ((const f32x4*)sh)[l];
  u16x4 wq;
#pragma unroll
  for (int j = 0; j < 4; ++j) wq[j] = f2bf(cw[j] * (1.f + s4[j]));
  const int wr = o >> 6, m = (o >> 4) & 3, lr = o & 15;
  const int kk = l >> 3, g = (l >> 1) & 3, jb = 4 * (l & 1);
  *(u16x4*)(wp + (size_t)b * 65536 + (((wr * 4 + m) * 8 + kk) * 512 + g * 128 + lr * 8 + jb)) = wq;
  float dd = cw[0] * h4[0] + cw[1] * h4[1] + cw[2] * h4[2] + cw[3] * h4[3];
#pragma unroll
  for (int off = 32; off; off >>= 1) dd += __shfl_down(dd, off);
  if (l == 0) dvec[b * 256 + o] = dd + conv_b[o];
}

// ---------------------------------------------------------------------------
// K3: fused rms + GEMM + selu.  grid(64,32): block = (64-wide s-tile, batch b).
// 512 thr = 8 waves. Phase-0 x-staging via global_load_lds (fire-and-forget
// DMA, deep queue, zero VGPR) into WAVE-PRIVATE staging slots, counted
// vmcnt(2) waits (T4: never drain mid-pipeline), zero barriers until the
// single pre-GEMM sync. GEMM/epilogue = the verified r5 structure.
// LDS ~68.9 KB -> 2 blocks/CU. All x chunks 256 B (no DRAM inflation).
// ---------------------------------------------------------------------------
__global__ __launch_bounds__(512, 4) void k_main(const float* __restrict__ x,
                                                 const unsigned short* __restrict__ wp,
                                                 const float* __restrict__ dvec,
                                                 float* __restrict__ out) {
  constexpr int HW = 4096;
  // staging: [8 waves][2 slots][2 instrs][1056 B] (1 KB payload + 32 B pad)
  __shared__ __align__(16) unsigned char stg[8 * 2 * 2 * 1056];  // 33792 B
  __shared__ __align__(16) unsigned short lds_bt[64 * 256];      // B swizzled, 32 KB
  __shared__ float lds_part[8][64];
  __shared__ float lds_rms[64];

  const int t = threadIdx.x;
  const int b = blockIdx.y;
  const int s0 = blockIdx.x * 64;
  const int w = t >> 6, lane = t & 63;

  const float* xb = x + (size_t)b * (256 * HW) + s0;
  unsigned char* stg_w = stg + w * (2 * 2112);

  float ss[8] = {0.f, 0.f, 0.f, 0.f, 0.f, 0.f, 0.f, 0.f};

  // issue one c-quarter (8 rows of this wave) as 2 x 1KB global_load_lds
#define ISSUE(Q, SLOT)                                                                   \
  {                                                                                      \
    _Pragma("unroll") for (int i = 0; i < 2; ++i) {                                      \
      const float* gp = xb + (size_t)((Q)*64 + w * 8 + i * 4 + (lane >> 4)) * HW +       \
                        (lane & 15) * 4;                                                 \
      void* lp = stg_w + (SLOT)*2112 + i * 1056;                                         \
      __builtin_amdgcn_global_load_lds((const __attribute__((address_space(1))) void*)gp,\
                                       (__attribute__((address_space(3))) void*)lp, 16,  \
                                       0, 0);                                            \
    }                                                                                    \
  }

  // transpose one staged quarter: lane -> row r=lane>>3, s-span (lane&7)*8..+7
#define TRANS(Q, SLOT)                                                                   \
  {                                                                                      \
    const int r = lane >> 3;                                                             \
    const float* sp =                                                                    \
        (const float*)(stg_w + (SLOT)*2112 + (r >> 2) * 1056 + (r & 3) * 256 +           \
                       (lane & 7) * 32);                                                 \
    f32x4 v0 = *(const f32x4*)sp;                                                        \
    f32x4 v1 = *((const f32x4*)sp + 1);                                                  \
    const int c = (Q)*64 + w * 8 + r;                                                    \
    const int sb = (lane & 7) * 8;                                                       \
    _Pragma("unroll") for (int j = 0; j < 4; ++j) {                                      \
      int s = sb + j;                                                                    \
      lds_bt[s * 256 + (c ^ (((s >> 1) & 7) << 3))] = f2bf(v0[j]);                       \
      ss[j] += v0[j] * v0[j];                                                            \
    }                                                                                    \
    _Pragma("unroll") for (int j = 0; j < 4; ++j) {                                      \
      int s = sb + 4 + j;                                                                \
      lds_bt[s * 256 + (c ^ (((s >> 1) & 7) << 3))] = f2bf(v1[j]);                       \
      ss[4 + j] += v1[j] * v1[j];                                                        \
    }                                                                                    \
  }

  ISSUE(0, 0);
  ISSUE(1, 1);
  asm volatile("s_waitcnt vmcnt(2)" ::: "memory");  // q0 landed
  TRANS(0, 0);
  ISSUE(2, 0);
  asm volatile("s_waitcnt vmcnt(2)" ::: "memory");  // q1 landed
  TRANS(1, 1);
  ISSUE(3, 1);
  asm volatile("s_waitcnt vmcnt(2)" ::: "memory");  // q2 landed
  TRANS(2, 0);
  asm volatile("s_waitcnt vmcnt(0)" ::: "memory");  // q3 landed
  TRANS(3, 1);
#undef ISSUE
#undef TRANS

  // per-s sumsq partials: reduce over lane bits 3,4,5 (rows within wave)
#pragma unroll
  for (int off = 8; off <= 32; off <<= 1) {
#pragma unroll
    for (int j = 0; j < 8; ++j) ss[j] += __shfl_xor(ss[j], off);
  }
  if (lane < 8) {
    f32x4 p0 = {ss[0], ss[1], ss[2], ss[3]}, p1 = {ss[4], ss[5], ss[6], ss[7]};
    *(f32x4*)&lds_part[w][lane * 8] = p0;
    *(f32x4*)&lds_part[w][lane * 8 + 4] = p1;
  }
  __syncthreads();                        // lds_bt + lds_part ready
  if (t < 64) {
    float sum = 0.f;
#pragma unroll
    for (int q = 0; q < 8; ++q) sum += lds_part[q][t];
    lds_rms[t] = rsqrtf(sum * (1.0f / 256.0f) + 1e-6f);
  }

  // ---- GEMM (verified r5 structure): A from L2 staged wp, B from lds_bt ----
  const unsigned short* A2 = wp + (size_t)b * 65536;
  const int wr = w >> 1, wc = w & 1;
  const int lr = lane & 15, g = lane >> 4;
  f32x4 acc[4][2] = {};
  const int sA = 32 * wc + lr;
  const int sB = sA + 16;
  const unsigned swA = ((sA >> 1) & 7) << 3;
  const unsigned swB = ((sB >> 1) & 7) << 3;

#pragma unroll
  for (int kk = 0; kk < 8; ++kk) {
    s16x8 af[4];
#pragma unroll
    for (int m = 0; m < 4; ++m)
      af[m] = *(const s16x8*)(A2 + (((wr * 4 + m) * 8 + kk) * 512 + lane * 8));

    const int c0 = kk * 32 + g * 8;
    s16x8 b0 = *(const s16x8*)&lds_bt[sA * 256 + (c0 ^ swA)];
    s16x8 b1 = *(const s16x8*)&lds_bt[sB * 256 + (c0 ^ swB)];

#pragma unroll
    for (int m = 0; m < 4; ++m) {
      acc[m][0] = __builtin_amdgcn_mfma_f32_16x16x32_bf16(af[m], b0, acc[m][0], 0, 0, 0);
      acc[m][1] = __builtin_amdgcn_mfma_f32_16x16x32_bf16(af[m], b1, acc[m][1], 0, 0, 0);
    }
  }

  __syncthreads();                        // lds_rms ready

  // ---- epilogue: y = rms*G + d; selu via v_exp ----
  float* ob = out + (size_t)b * (256 * HW) + s0;
#pragma unroll
  for (int m = 0; m < 4; ++m) {
    const int o0 = 64 * wr + 16 * m + 4 * g;
    const f32x4 dv = *(const f32x4*)(dvec + (size_t)b * 256 + o0);
#pragma unroll
    for (int n = 0; n < 2; ++n) {
      const int s = 32 * wc + 16 * n + lr;
      const float rr = lds_rms[s];
#pragma unroll
      for (int r = 0; r < 4; ++r) {
        float v = rr * acc[m][n][r] + dv[r];
        float res = v > 0.f ? 1.0507009873554805f * v
                            : 1.7580993408473766f * (__expf(v) - 1.f);
        ob[(size_t)(o0 + r) * HW + s] = res;
      }
    }
  }
}

// ---------------------------------------------------------------------------
extern "C" void kernel_launch(void* const* d_in, const int* in_sizes, int n_in,
                              void* d_out, int out_size, void* d_ws, size_t ws_size,
                              hipStream_t stream) {
  const float* x      = (const float*)d_in[0];
  const float* emb    = (const float*)d_in[1];
  const float* ada_w  = (const float*)d_in[2];
  const float* ada_b  = (const float*)d_in[3];
  const float* conv_w = (const float*)d_in[4];
  const float* conv_b = (const float*)d_in[5];
  float* out = (float*)d_out;

  float* mod  = (float*)d_ws;                               // 32*512 f32
  float* dvec = mod + 32 * 512;                             // 32*256 f32
  unsigned short* wp = (unsigned short*)(dvec + 32 * 256);  // 32*256*256 bf16 (staged layout)

  k_mod<<<dim3(32), 512, 0, stream>>>(emb, ada_w, ada_b, mod);
  k_prep<<<dim3(64, 32), 256, 0, stream>>>(mod, conv_w, conv_b, wp, dvec);
  k_main<<<dim3(64, 32), 512, 0, stream>>>(x, wp, dvec, out);
}